// Round 4
// baseline (1332.781 us; speedup 1.0000x reference)
//
#include <hip/hip_runtime.h>
#include <hip/hip_bf16.h>

// OrbitalGenerator: 1024 independent [128x256] slices through a 4-layer MPNN.
// One block per orbital, 8 waves. Each wave owns a 16-row m-tile (wave*16).
// feats lives in registers (f32x4 fr[16], static-indexed, seeds GEMM2 MFMA
// accumulator chains). h/vals/msg/t ping-pong through 128KB LDS (bf16).
// KEY CHANGE vs R3: hot layer-loop body shrunk ~4x (runtime nti/mt loops with
// explicit double-buffered prefetch, #pragma unroll 1 on layer loop) to fit
// L1I and kill instruction-stream starvation; barriers 5->4 per layer.

#define O_TOT 1024

typedef __bf16 bf16x8 __attribute__((ext_vector_type(8)));
typedef float f32x4 __attribute__((ext_vector_type(4)));

static __device__ __forceinline__ unsigned short f2bf(float f) {
  __bf16 b = (__bf16)f;
  unsigned short u;
  __builtin_memcpy(&u, &b, 2);
  return u;
}
static __device__ __forceinline__ float bf2f(unsigned short u) {
  unsigned int x = ((unsigned int)u) << 16;
  float f;
  __builtin_memcpy(&f, &x, 4);
  return f;
}
static __device__ __forceinline__ float ftanh(float x) {
  float e = __expf(2.f * x);
  return 1.f - 2.f * __builtin_amdgcn_rcpf(e + 1.f);
}

struct alignas(8) US4 { unsigned short a, b, c, d; };

// XOR swizzles with 2 row bits -> 16 distinct 16B slots per 16 consecutive rows.
static __device__ __forceinline__ int swzA(int row, int cb) {  // [128][512B]
  return row * 512 + (cb ^ ((row & 7) << 4) ^ (((row >> 3) & 1) << 5));
}
static __device__ __forceinline__ int swzV(int row, int cb) {  // [256][256B]
  return row * 256 + (cb ^ ((row & 7) << 4) ^ (((row >> 3) & 1) << 5));
}

// ---------------- setup kernels (unchanged) ----------------

__global__ void k_orbmap(const int* __restrict__ charges, const int* __restrict__ n_up_p,
                         const int* __restrict__ n_down_p, int* __restrict__ orb_nuc,
                         int* __restrict__ orb_t) {
  __shared__ int off[129];
  __shared__ int prec[128];
  int tid = threadIdx.x;
  if (tid == 0) {
    int a = 0;
    for (int n = 0; n < 128; ++n) { off[n] = a; a += charges[n]; }
    off[128] = a;
  }
  if (tid < 128) prec[tid] = charges[tid] * (charges[tid] - 1) / 2;
  __syncthreads();
  int nu = *n_up_p, nd = *n_down_p;
  for (int o = tid; o < O_TOT; o += 256) {
    int e;
    if (o < nu) e = o;
    else if (o < 512) e = o + nd;
    else if (o < 512 + nd) e = o + nu - 512;
    else e = o;
    int nn = -1, tt = 0;
    for (int n = 0; n < 128; ++n) {
      if (e >= off[n] && e < off[n + 1]) { nn = n; tt = prec[n] + (e - off[n]); }
    }
    orb_nuc[o] = nn;
    orb_t[o] = tt;
  }
}

__global__ void k_ew(const float* __restrict__ coords, const float* __restrict__ W_edge,
                     unsigned short* __restrict__ ewb) {
  int i = blockIdx.x, j = threadIdx.x;
  float dx = coords[i * 3 + 0] - coords[j * 3 + 0];
  float dy = coords[i * 3 + 1] - coords[j * 3 + 1];
  float dz = coords[i * 3 + 2] - coords[j * 3 + 2];
  float norm = sqrtf(dx * dx + dy * dy + dz * dz + 1e-12f);
  float inv = 1.f / (1.f + norm);
  float e[7];
  e[0] = dx * inv; e[1] = dy * inv; e[2] = dz * inv;
  e[3] = log1pf(norm);
  e[4] = 1.f / (1.f + expf(-(norm - 2.f)));
  e[5] = 1.f / (1.f + expf(-(norm - 4.f)));
  e[6] = 1.f / (1.f + expf(-(norm - 6.f)));
  for (int l = 0; l < 4; ++l)
    for (int h = 0; h < 8; ++h) {
      float s = 0.f;
      for (int k = 0; k < 7; ++k) s += e[k] * W_edge[(l * 7 + k) * 8 + h];
      ewb[((l * 8 + h) * 128 + i) * 128 + j] = f2bf(s);
    }
}

__global__ void k_wt(const float* __restrict__ Wv, const float* __restrict__ Wo,
                     unsigned short* __restrict__ WvT, unsigned short* __restrict__ WoT) {
  int idx = blockIdx.x * 256 + threadIdx.x;  // 4*256*256
  int l = idx >> 16, r = idx & 65535, g = r >> 8, f = r & 255;
  int src = (l << 16) + f * 256 + g;
  WvT[idx] = f2bf(Wv[src]);
  WoT[idx] = f2bf(Wo[src]);
}

// nucbT[l][g][i] = nuc_feats[i,:] @ W_nuc[l][:,g]  (fp32, transposed)
__global__ void k_nucbT(const float* __restrict__ nuc_feats, const float* __restrict__ W_nuc,
                        float* __restrict__ nucbT) {
  int b = blockIdx.x;  // l*128 + i
  int l = b >> 7, i = b & 127;
  int g = threadIdx.x;
  __shared__ float row[256];
  row[g] = nuc_feats[i * 256 + g];
  __syncthreads();
  const float* Wn = W_nuc + l * 65536;
  float s = 0.f;
  for (int f = 0; f < 256; ++f) s += row[f] * Wn[f * 256 + g];
  nucbT[(l * 256 + g) * 128 + i] = s;
}

// ---------------- fused main kernel ----------------

__global__ __launch_bounds__(512, 2) void k_main(
    float* __restrict__ feats,               // d_out [1024][128][256] fp32
    const float* __restrict__ W_orb,         // [136][256]
    const unsigned short* __restrict__ WvT,  // [4][256][256] bf16 (g-major)
    const unsigned short* __restrict__ WoT,  // [4][256][256] bf16 (g-major)
    const unsigned short* __restrict__ ewb,  // [4][8][128][128] bf16
    const float* __restrict__ nucbT,         // [4][256][128] fp32
    const int* __restrict__ orb_nuc, const int* __restrict__ orb_t) {
  __shared__ char SBUF[131072];     // s1: h/msg [128][512B]; s2: valsT [256][256B] / t
  __shared__ float ln2[8][128][2];  // LN2 per-head partials [head][row][s,ss]
  __shared__ float red[8];

  char* s1 = SBUF;
  char* s2 = SBUF + 65536;

  const int o = blockIdx.x;
  const int tid = threadIdx.x;
  const int wave = tid >> 6;
  const int lane = tid & 63;
  const int l16 = lane & 15;
  const int kgrp = (lane >> 4) << 3;  // A/B fragment k-offset: 0,8,16,24
  const int rgrp = (lane >> 4) << 2;  // D fragment row group: 0,4,8,12
  const int w16 = wave * 16;          // this wave's 16 output rows

  const int nn = orb_nuc[o];
  const int tt = orb_t[o];
  float* fo = feats + (size_t)o * 32768;

  // feats in registers: fr[nti][r] = feats[w16+rgrp+r][nti*16+l16]
  f32x4 fr[16];
#pragma unroll
  for (int nti = 0; nti < 16; ++nti) {
    f32x4 v = {0.f, 0.f, 0.f, 0.f};
#pragma unroll
    for (int r = 0; r < 4; ++r)
      if (w16 + rgrp + r == nn) v[r] = W_orb[tt * 256 + nti * 16 + l16];
    fr[nti] = v;
  }

#pragma unroll 1
  for (int l = 0; l < 4; ++l) {
    // ---- LN1 (wave-local, single phase): stats from fr + h write to S1 ----
    {
      float s[4] = {0, 0, 0, 0}, q[4] = {0, 0, 0, 0};
#pragma unroll
      for (int nti = 0; nti < 16; ++nti)
#pragma unroll
        for (int r = 0; r < 4; ++r) {
          float v = fr[nti][r];
          s[r] += v; q[r] += v * v;
        }
#pragma unroll
      for (int of = 1; of < 16; of <<= 1)
#pragma unroll
        for (int r = 0; r < 4; ++r) {
          s[r] += __shfl_xor(s[r], of);
          q[r] += __shfl_xor(q[r], of);
        }
      float mean[4], maxv = 0.f;
#pragma unroll
      for (int r = 0; r < 4; ++r) {
        mean[r] = s[r] * (1.f / 256.f);
        float var = q[r] * (1.f / 256.f) - mean[r] * mean[r];
        maxv = fmaxf(maxv, var);
      }
      maxv = fmaxf(maxv, __shfl_xor(maxv, 16));
      maxv = fmaxf(maxv, __shfl_xor(maxv, 32));
      if (lane == 0) red[wave] = maxv;
#pragma unroll
      for (int nti = 0; nti < 16; ++nti)
#pragma unroll
        for (int r = 0; r < 4; ++r)
          *(unsigned short*)(s1 + swzA(w16 + rgrp + r, (nti * 16 + l16) * 2)) =
              f2bf(fr[nti][r] - mean[r]);
    }
    __syncthreads();  // B2: S1(h) + red ready

    // ---- GEMM1: valsT[g][n] = rstd*(h @ W_val); m-tile w16, all 256 g ----
    {
      float mv = red[0];
#pragma unroll
      for (int w = 1; w < 8; ++w) mv = fmaxf(mv, red[w]);
      const float rstd = rsqrtf(mv + 1.f);
      const unsigned short* Wl = WvT + l * 65536;
      bf16x8 A[8];
#pragma unroll
      for (int k0 = 0; k0 < 8; ++k0)
        A[k0] = *(const bf16x8*)(s1 + swzA(w16 + l16, (k0 * 32 + kgrp) * 2));

      auto body = [&](int nti, const bf16x8* b) {
        f32x4 acc = {0.f, 0.f, 0.f, 0.f};
#pragma unroll
        for (int k0 = 0; k0 < 8; ++k0)
          acc = __builtin_amdgcn_mfma_f32_16x16x32_bf16(A[k0], b[k0], acc, 0, 0, 0);
        const int gg = nti * 16 + l16;
        US4 ov{f2bf(acc[0] * rstd), f2bf(acc[1] * rstd), f2bf(acc[2] * rstd),
               f2bf(acc[3] * rstd)};
        *(US4*)(s2 + swzV(gg, (w16 + rgrp) * 2)) = ov;
      };

      bf16x8 b0[8], b1[8];
#pragma unroll
      for (int k0 = 0; k0 < 8; ++k0)
        b0[k0] = *(const bf16x8*)(Wl + l16 * 256 + kgrp + k0 * 32);
#pragma unroll 1
      for (int p = 0; p < 8; ++p) {
        const int nti1 = 2 * p + 1, nti2 = (2 * p + 2) & 15;
#pragma unroll
        for (int k0 = 0; k0 < 8; ++k0)
          b1[k0] = *(const bf16x8*)(Wl + (nti1 * 16 + l16) * 256 + kgrp + k0 * 32);
        body(2 * p, b0);
#pragma unroll
        for (int k0 = 0; k0 < 8; ++k0)
          b0[k0] = *(const bf16x8*)(Wl + (nti2 * 16 + l16) * 256 + kgrp + k0 * 32);
        body(nti1, b1);
      }
    }
    __syncthreads();  // B3: S2(valsT) ready

    // ---- MSG: msg[i][f] = sum_j ew[h][i][j]*valsT[f][j] + nucbT[f][i] ----
    //      wave = head; in-epilogue LN2 partial stats -> ln2
    {
      const unsigned short* ewh = ewb + (l * 8 + wave) * 16384;
      const float* nbT = nucbT + l * 32768;
      const int f0 = wave * 32 + l16;
      const int f1 = f0 + 16;
      bf16x8 B0[4], B1[4];  // this head's valsT rows, full K=128
#pragma unroll
      for (int k0 = 0; k0 < 4; ++k0) {
        B0[k0] = *(const bf16x8*)(s2 + swzV(wave * 32 + l16, (k0 * 32 + kgrp) * 2));
        B1[k0] = *(const bf16x8*)(s2 + swzV(wave * 32 + 16 + l16, (k0 * 32 + kgrp) * 2));
      }

      auto body = [&](int i0, const bf16x8* a) {
        f32x4 acc0 = {0.f, 0.f, 0.f, 0.f}, acc1 = {0.f, 0.f, 0.f, 0.f};
#pragma unroll
        for (int k0 = 0; k0 < 4; ++k0) {
          acc0 = __builtin_amdgcn_mfma_f32_16x16x32_bf16(a[k0], B0[k0], acc0, 0, 0, 0);
          acc1 = __builtin_amdgcn_mfma_f32_16x16x32_bf16(a[k0], B1[k0], acc1, 0, 0, 0);
        }
        const f32x4 nb0 = *(const f32x4*)(nbT + f0 * 128 + i0 + rgrp);
        const f32x4 nb1 = *(const f32x4*)(nbT + f1 * 128 + i0 + rgrp);
        float sp[4], qp[4];
#pragma unroll
        for (int r = 0; r < 4; ++r) {
          const float v0 = acc0[r] + nb0[r];
          const float v1 = acc1[r] + nb1[r];
          *(unsigned short*)(s1 + swzA(i0 + rgrp + r, f0 * 2)) = f2bf(v0);
          *(unsigned short*)(s1 + swzA(i0 + rgrp + r, f1 * 2)) = f2bf(v1);
          sp[r] = v0 + v1;
          qp[r] = v0 * v0 + v1 * v1;
        }
#pragma unroll
        for (int of = 1; of < 16; of <<= 1)
#pragma unroll
          for (int r = 0; r < 4; ++r) {
            sp[r] += __shfl_xor(sp[r], of);
            qp[r] += __shfl_xor(qp[r], of);
          }
        if (l16 == 0) {
#pragma unroll
          for (int r = 0; r < 4; ++r) {
            ln2[wave][i0 + rgrp + r][0] = sp[r];
            ln2[wave][i0 + rgrp + r][1] = qp[r];
          }
        }
      };

      bf16x8 a0[4], a1[4];
#pragma unroll
      for (int k0 = 0; k0 < 4; ++k0)
        a0[k0] = *(const bf16x8*)(ewh + l16 * 128 + k0 * 32 + kgrp);
#pragma unroll 1
      for (int p = 0; p < 4; ++p) {
        const int i0a = p * 32, i0b = p * 32 + 16, i0n = (p * 32 + 32) & 127;
#pragma unroll
        for (int k0 = 0; k0 < 4; ++k0)
          a1[k0] = *(const bf16x8*)(ewh + (i0b + l16) * 128 + k0 * 32 + kgrp);
        body(i0a, a0);
#pragma unroll
        for (int k0 = 0; k0 < 4; ++k0)
          a0[k0] = *(const bf16x8*)(ewh + (i0n + l16) * 128 + k0 * 32 + kgrp);
        body(i0b, a1);
      }
    }
    __syncthreads();  // B4: S1(msg) + ln2 ready

    // ---- LN2 combine (redundant per wave) + pass B: t = tanh(...) -> S2 ----
    {
      float s0 = 0.f, q0 = 0.f, s1v = 0.f, q1v = 0.f;
#pragma unroll
      for (int h = 0; h < 8; ++h) {
        s0 += ln2[h][lane][0];        q0 += ln2[h][lane][1];
        s1v += ln2[h][lane + 64][0];  q1v += ln2[h][lane + 64][1];
      }
      const float mean_a = s0 * (1.f / 256.f);
      const float mean_b = s1v * (1.f / 256.f);
      float v0 = q0 * (1.f / 256.f) - mean_a * mean_a;
      float v1 = q1v * (1.f / 256.f) - mean_b * mean_b;
      float mv = fmaxf(v0, v1);
#pragma unroll
      for (int of = 1; of < 64; of <<= 1) mv = fmaxf(mv, __shfl_xor(mv, of));
      const float rstd2 = rsqrtf(mv + 1.f);
      const float meansel = (wave >= 4) ? mean_b : mean_a;
#pragma unroll 2
      for (int r = 0; r < 16; ++r) {
        const int n = w16 + r;
        const float mn = __shfl(meansel, ((wave & 3) << 4) + r);
        US4 x4 = *(const US4*)(s1 + swzA(n, lane * 8));
        US4 t4{f2bf(ftanh((bf2f(x4.a) - mn) * rstd2)),
               f2bf(ftanh((bf2f(x4.b) - mn) * rstd2)),
               f2bf(ftanh((bf2f(x4.c) - mn) * rstd2)),
               f2bf(ftanh((bf2f(x4.d) - mn) * rstd2))};
        *(US4*)(s2 + swzA(n, lane * 8)) = t4;
      }
    }
    __syncthreads();  // B5: S2(t) ready

    // ---- GEMM2: fr = t @ W_out + fr (fr static-indexed => full unroll) ----
    {
      const unsigned short* Wl = WoT + l * 65536;
      bf16x8 A2[8];
#pragma unroll
      for (int k0 = 0; k0 < 8; ++k0)
        A2[k0] = *(const bf16x8*)(s2 + swzA(w16 + l16, (k0 * 32 + kgrp) * 2));
#pragma unroll
      for (int nti = 0; nti < 16; ++nti) {
        const unsigned short* brow = Wl + (nti * 16 + l16) * 256 + kgrp;
        bf16x8 b[8];
#pragma unroll
        for (int k0 = 0; k0 < 8; ++k0) b[k0] = *(const bf16x8*)(brow + k0 * 32);
        f32x4 acc = fr[nti];
#pragma unroll
        for (int k0 = 0; k0 < 8; ++k0)
          acc = __builtin_amdgcn_mfma_f32_16x16x32_bf16(A2[k0], b[k0], acc, 0, 0, 0);
        fr[nti] = acc;
      }
    }
    // no barrier: next LDS touch is LN1 h-write (S1), safe — all S1 readers
    // (passB) finished before B5; GEMM2 only reads S2, fenced by next B2.
  }

  // ---- final store: stage fp32 through LDS for coalesced float4 stores ----
  __syncthreads();
  float* stage = (float*)SBUF;
#pragma unroll
  for (int nti = 0; nti < 16; ++nti)
#pragma unroll
    for (int r = 0; r < 4; ++r)
      stage[(w16 + rgrp + r) * 256 + nti * 16 + l16] = fr[nti][r];
  __syncthreads();
#pragma unroll 4
  for (int it = 0; it < 16; ++it) {
    const int idx = (it * 512 + tid) * 4;
    *(f32x4*)(fo + idx) = *(const f32x4*)(stage + idx);
  }
}

// ---------------- launcher ----------------

extern "C" void kernel_launch(void* const* d_in, const int* in_sizes, int n_in,
                              void* d_out, int out_size, void* d_ws, size_t ws_size,
                              hipStream_t stream) {
  const float* coords = (const float*)d_in[0];
  const int* charges = (const int*)d_in[1];
  const int* n_up = (const int*)d_in[3];
  const int* n_down = (const int*)d_in[4];
  const float* nuc_feats = (const float*)d_in[5];
  const float* W_orb = (const float*)d_in[7];
  const float* W_edge = (const float*)d_in[8];
  const float* W_val = (const float*)d_in[9];
  const float* W_nuc = (const float*)d_in[10];
  const float* W_out = (const float*)d_in[11];
  float* out = (float*)d_out;

  char* ws = (char*)d_ws;
  int* orb_nuc = (int*)ws;                                        // 4KB
  int* orb_t = (int*)(ws + 4096);                                 // 4KB
  unsigned short* ewb = (unsigned short*)(ws + 8192);             // 1MB
  unsigned short* WvT = (unsigned short*)(ws + 8192 + 1048576);   // 512KB
  unsigned short* WoT = WvT + 262144;                             // 512KB
  float* nucbT = (float*)(ws + 8192 + 1048576 + 1048576);         // 512KB

  k_orbmap<<<dim3(1), dim3(256), 0, stream>>>(charges, n_up, n_down, orb_nuc, orb_t);
  k_ew<<<dim3(128), dim3(128), 0, stream>>>(coords, W_edge, ewb);
  k_wt<<<dim3(1024), dim3(256), 0, stream>>>(W_val, W_out, WvT, WoT);
  k_nucbT<<<dim3(512), dim3(256), 0, stream>>>(nuc_feats, W_nuc, nucbT);
  k_main<<<dim3(O_TOT), dim3(512), 0, stream>>>(out, W_orb, WvT, WoT, ewb, nucbT,
                                                orb_nuc, orb_t);
}